// Round 1
// baseline (559.318 us; speedup 1.0000x reference)
//
#include <hip/hip_runtime.h>

// MaxUnpooling2D scatter-add:
//   out[mask[i]] += updates[i]  over 8,388,608 elements, out_size = 33,554,432 fp32.
// Harness poisons d_out with 0xAA before every timed call -> must zero it here.

__global__ void zero_out_kernel(float4* __restrict__ out, int n4) {
    int i = blockIdx.x * blockDim.x + threadIdx.x;
    if (i < n4) out[i] = make_float4(0.f, 0.f, 0.f, 0.f);
}

__global__ void scatter_add_kernel(const float4* __restrict__ upd,
                                   const int4* __restrict__ mask,
                                   float* __restrict__ out, int n4) {
    int i = blockIdx.x * blockDim.x + threadIdx.x;
    if (i < n4) {
        float4 u = upd[i];
        int4 m = mask[i];
        atomicAdd(out + m.x, u.x);
        atomicAdd(out + m.y, u.y);
        atomicAdd(out + m.z, u.z);
        atomicAdd(out + m.w, u.w);
    }
}

extern "C" void kernel_launch(void* const* d_in, const int* in_sizes, int n_in,
                              void* d_out, int out_size, void* d_ws, size_t ws_size,
                              hipStream_t stream) {
    const float* updates = (const float*)d_in[0];
    const int*   mask    = (const int*)d_in[1];
    float* out = (float*)d_out;

    const int n = in_sizes[0];        // 8,388,608 (divisible by 4)
    const int n4 = n >> 2;            // 2,097,152
    const int o4 = out_size >> 2;     // 8,388,608 (out_size divisible by 4)

    const int block = 256;
    // 1) zero the output (poisoned with 0xAA by the harness each call)
    zero_out_kernel<<<(o4 + block - 1) / block, block, 0, stream>>>(
        (float4*)out, o4);
    // 2) scatter-add with vectorized input reads
    scatter_add_kernel<<<(n4 + block - 1) / block, block, 0, stream>>>(
        (const float4*)updates, (const int4*)mask, out, n4);
}

// Round 2
// 408.985 us; speedup vs baseline: 1.3676x; 1.3676x over previous
//
#include <hip/hip_runtime.h>

// MaxUnpooling2D scatter-add: out[mask[i]] += updates[i]
//   n = 8,388,608 updates (fp32) + indices (int32), out_size = 33,554,432 fp32 (134 MB).
// Strategy: bin-by-output-region so the random atomics happen in LDS, not at a
// missing L2 line. Phase 2 writes every output element -> no separate zero pass.

#define NB        2048                  // buckets = out_size / RB
#define RB        16384                 // floats per bucket region (64 KB)
#define CAP       5120                  // pair capacity per bucket (mean 4096, 16 sigma slack)
#define P1_BLOCKS 512
#define IPB       16384                 // items per phase-1 block = n / P1_BLOCKS

__global__ void zero_cnt_kernel(unsigned int* __restrict__ cnt) {
    int i = blockIdx.x * blockDim.x + threadIdx.x;
    if (i < NB) cnt[i] = 0u;
}

__global__ __launch_bounds__(256) void partition_kernel(
        const float4* __restrict__ upd4,
        const int4*  __restrict__ mask4,
        unsigned int* __restrict__ gcnt,
        uint2*        __restrict__ pairs) {
    __shared__ unsigned int hist[NB];
    __shared__ unsigned int base[NB];
    const int t = threadIdx.x;
    const int start4 = blockIdx.x * (IPB / 4);

    for (int b = t; b < NB; b += 256) hist[b] = 0u;
    __syncthreads();

    // Pass A: per-block histogram (mask only)
    #pragma unroll
    for (int j = 0; j < IPB / 4 / 256; ++j) {
        int4 m = mask4[start4 + j * 256 + t];
        atomicAdd(&hist[((unsigned)m.x) >> 14], 1u);
        atomicAdd(&hist[((unsigned)m.y) >> 14], 1u);
        atomicAdd(&hist[((unsigned)m.z) >> 14], 1u);
        atomicAdd(&hist[((unsigned)m.w) >> 14], 1u);
    }
    __syncthreads();

    // Reserve global ranges: one atomic per (block, bucket)
    for (int b = t; b < NB; b += 256) {
        unsigned h = hist[b];
        base[b] = h ? atomicAdd(&gcnt[b], h) : 0u;
        hist[b] = 0u;  // reuse as running intra-block counter
    }
    __syncthreads();

    // Pass B: write (offset, value) pairs into reserved ranges
    #pragma unroll
    for (int j = 0; j < IPB / 4 / 256; ++j) {
        const int i4 = start4 + j * 256 + t;
        int4   m = mask4[i4];
        float4 u = upd4[i4];
        {
            unsigned b = ((unsigned)m.x) >> 14;
            unsigned pos = base[b] + atomicAdd(&hist[b], 1u);
            if (pos < CAP) pairs[(size_t)b * CAP + pos] =
                make_uint2(((unsigned)m.x) & (RB - 1u), __float_as_uint(u.x));
        }
        {
            unsigned b = ((unsigned)m.y) >> 14;
            unsigned pos = base[b] + atomicAdd(&hist[b], 1u);
            if (pos < CAP) pairs[(size_t)b * CAP + pos] =
                make_uint2(((unsigned)m.y) & (RB - 1u), __float_as_uint(u.y));
        }
        {
            unsigned b = ((unsigned)m.z) >> 14;
            unsigned pos = base[b] + atomicAdd(&hist[b], 1u);
            if (pos < CAP) pairs[(size_t)b * CAP + pos] =
                make_uint2(((unsigned)m.z) & (RB - 1u), __float_as_uint(u.z));
        }
        {
            unsigned b = ((unsigned)m.w) >> 14;
            unsigned pos = base[b] + atomicAdd(&hist[b], 1u);
            if (pos < CAP) pairs[(size_t)b * CAP + pos] =
                make_uint2(((unsigned)m.w) & (RB - 1u), __float_as_uint(u.w));
        }
    }
}

__global__ __launch_bounds__(256) void unbin_kernel(
        const unsigned int* __restrict__ gcnt,
        const uint2*        __restrict__ pairs,
        float4*             __restrict__ out4) {
    extern __shared__ float tile[];   // RB floats = 64 KB (dynamic)
    const int b = blockIdx.x, t = threadIdx.x;
    float4* t4 = (float4*)tile;

    for (int j = t; j < RB / 4; j += 256) t4[j] = make_float4(0.f, 0.f, 0.f, 0.f);
    __syncthreads();

    unsigned c = gcnt[b];
    if (c > CAP) c = CAP;
    const uint2* p = pairs + (size_t)b * CAP;
    for (unsigned i = t; i < c; i += 256) {
        uint2 e = p[i];
        atomicAdd(&tile[e.x], __uint_as_float(e.y));
    }
    __syncthreads();

    for (int j = t; j < RB / 4; j += 256)
        out4[(size_t)b * (RB / 4) + j] = t4[j];
}

// ---- fallback (direct atomics) if workspace is too small ----
__global__ void zero_out_kernel(float4* __restrict__ out, int n4) {
    int i = blockIdx.x * blockDim.x + threadIdx.x;
    if (i < n4) out[i] = make_float4(0.f, 0.f, 0.f, 0.f);
}
__global__ void scatter_add_kernel(const float4* __restrict__ upd,
                                   const int4* __restrict__ mask,
                                   float* __restrict__ out, int n4) {
    int i = blockIdx.x * blockDim.x + threadIdx.x;
    if (i < n4) {
        float4 u = upd[i];
        int4 m = mask[i];
        atomicAdd(out + m.x, u.x);
        atomicAdd(out + m.y, u.y);
        atomicAdd(out + m.z, u.z);
        atomicAdd(out + m.w, u.w);
    }
}

extern "C" void kernel_launch(void* const* d_in, const int* in_sizes, int n_in,
                              void* d_out, int out_size, void* d_ws, size_t ws_size,
                              hipStream_t stream) {
    const float* updates = (const float*)d_in[0];
    const int*   mask    = (const int*)d_in[1];
    float* out = (float*)d_out;
    const int n  = in_sizes[0];          // 8,388,608
    const int n4 = n >> 2;
    const int o4 = out_size >> 2;

    const size_t need = (size_t)NB * 4 + (size_t)NB * CAP * sizeof(uint2);
    if (ws_size >= need && out_size == NB * RB && n == P1_BLOCKS * IPB) {
        unsigned int* gcnt = (unsigned int*)d_ws;
        uint2* pairs = (uint2*)((char*)d_ws + NB * 4);

        zero_cnt_kernel<<<(NB + 255) / 256, 256, 0, stream>>>(gcnt);
        partition_kernel<<<P1_BLOCKS, 256, 0, stream>>>(
            (const float4*)updates, (const int4*)mask, gcnt, pairs);
        unbin_kernel<<<NB, 256, RB * sizeof(float), stream>>>(
            gcnt, pairs, (float4*)out);
    } else {
        zero_out_kernel<<<(o4 + 255) / 256, 256, 0, stream>>>((float4*)out, o4);
        scatter_add_kernel<<<(n4 + 255) / 256, 256, 0, stream>>>(
            (const float4*)updates, (const int4*)mask, out, n4);
    }
}

// Round 3
// 268.753 us; speedup vs baseline: 2.0812x; 1.5218x over previous
//
#include <hip/hip_runtime.h>

// MaxUnpooling2D scatter-add: out[mask[i]] += updates[i]
//   n = 8,388,608 updates (fp32) + indices (int32), out_size = 33,554,432 fp32 (134 MB).
//
// v3: block-local counting sort in LDS -> fully coalesced pair writes in a
// [block][sorted-by-bucket] layout + packed per-(block,bucket) offset table.
// Unbin gathers chunks per bucket (scattered reads, L3-absorbed), accumulates
// in a 64 KB LDS tile with ds_add_f32, streams tile out (no zero pass needed).

#define NB        2048          // buckets; bucket = idx >> 14
#define NB_SHIFT  14
#define RB        16384         // floats per bucket output region (64 KB)
#define P1B       1024          // partition blocks
#define IPB       8192          // items per partition block (= n / P1B)

__global__ __launch_bounds__(256) void partition_kernel(
        const float4* __restrict__ upd4,
        const int4*   __restrict__ mask4,
        unsigned int* __restrict__ table,    // [P1B][NB] packed: start | cnt<<16
        uint2*        __restrict__ pairs) {  // [P1B][IPB]
    __shared__ unsigned int hb[NB];      // hist -> base/cursor
    __shared__ unsigned int tsum[256];
    __shared__ uint2 stage[IPB];         // 64 KB
    const int t = threadIdx.x;
    const int k = blockIdx.x;
    const int s4 = k * (IPB / 4);

    for (int b = t; b < NB; b += 256) hb[b] = 0u;
    __syncthreads();

    // Pass A: load mask once (kept in regs), LDS histogram
    int4 mm[IPB / 4 / 256];
    #pragma unroll
    for (int j = 0; j < IPB / 4 / 256; ++j) mm[j] = mask4[s4 + j * 256 + t];
    #pragma unroll
    for (int j = 0; j < IPB / 4 / 256; ++j) {
        atomicAdd(&hb[((unsigned)mm[j].x) >> NB_SHIFT], 1u);
        atomicAdd(&hb[((unsigned)mm[j].y) >> NB_SHIFT], 1u);
        atomicAdd(&hb[((unsigned)mm[j].z) >> NB_SHIFT], 1u);
        atomicAdd(&hb[((unsigned)mm[j].w) >> NB_SHIFT], 1u);
    }
    __syncthreads();

    // Block-wide exclusive scan of hb[NB]: per-thread serial(8) + Hillis-Steele(256)
    unsigned c[8], s = 0;
    #pragma unroll
    for (int j = 0; j < 8; ++j) { c[j] = hb[t * 8 + j]; s += c[j]; }
    tsum[t] = s;
    __syncthreads();
    #pragma unroll
    for (int d = 1; d < 256; d <<= 1) {
        unsigned v = (t >= d) ? tsum[t - d] : 0u;
        __syncthreads();
        tsum[t] += v;
        __syncthreads();
    }
    unsigned run = (t > 0) ? tsum[t - 1] : 0u;   // exclusive prefix
    #pragma unroll
    for (int j = 0; j < 8; ++j) {
        unsigned b = t * 8 + j;
        hb[b] = run;                              // base (becomes cursor)
        table[(size_t)k * NB + b] = run | (c[j] << 16);  // coalesced
        run += c[j];
    }
    __syncthreads();

    // Pass B: load updates, place (offset,value) into LDS staging at sorted pos
    float4 uu[IPB / 4 / 256];
    #pragma unroll
    for (int j = 0; j < IPB / 4 / 256; ++j) uu[j] = upd4[s4 + j * 256 + t];
    #pragma unroll
    for (int j = 0; j < IPB / 4 / 256; ++j) {
        #define PLACE(mi, vi) { \
            unsigned b_ = ((unsigned)(mi)) >> NB_SHIFT; \
            unsigned pos_ = atomicAdd(&hb[b_], 1u); \
            stage[pos_] = make_uint2(((unsigned)(mi)) & (RB - 1u), __float_as_uint(vi)); }
        PLACE(mm[j].x, uu[j].x)
        PLACE(mm[j].y, uu[j].y)
        PLACE(mm[j].z, uu[j].z)
        PLACE(mm[j].w, uu[j].w)
        #undef PLACE
    }
    __syncthreads();

    // Dump staging to block-private contiguous region: fully coalesced dwordx4
    const uint4* sp = (const uint4*)stage;
    uint4* dp = (uint4*)(pairs + (size_t)k * IPB);
    #pragma unroll
    for (int j = 0; j < IPB / 2 / 256; ++j) dp[j * 256 + t] = sp[j * 256 + t];
}

__global__ __launch_bounds__(256) void unbin_kernel(
        const unsigned int* __restrict__ table,
        const uint2*        __restrict__ pairs,
        float4*             __restrict__ out4) {
    extern __shared__ float tile[];   // RB floats = 64 KB
    const int b = blockIdx.x, t = threadIdx.x;
    float4* t4 = (float4*)tile;

    for (int j = t; j < RB / 4; j += 256) t4[j] = make_float4(0.f, 0.f, 0.f, 0.f);
    __syncthreads();

    // Gather this bucket's chunk from every source block
    unsigned e[P1B / 256];
    #pragma unroll
    for (int j = 0; j < P1B / 256; ++j)
        e[j] = table[(size_t)(t + j * 256) * NB + b];   // issue all together
    #pragma unroll
    for (int j = 0; j < P1B / 256; ++j) {
        unsigned start = e[j] & 0xFFFFu, cnt = e[j] >> 16;
        const uint2* p = pairs + (size_t)(t + j * 256) * IPB + start;
        for (unsigned i = 0; i < cnt; ++i) {
            uint2 pr = p[i];
            atomicAdd(&tile[pr.x], __uint_as_float(pr.y));
        }
    }
    __syncthreads();

    for (int j = t; j < RB / 4; j += 256)
        out4[(size_t)b * (RB / 4) + j] = t4[j];
}

// ---- fallback (direct atomics) if workspace/shape unexpected ----
__global__ void zero_out_kernel(float4* __restrict__ out, int n4) {
    int i = blockIdx.x * blockDim.x + threadIdx.x;
    if (i < n4) out[i] = make_float4(0.f, 0.f, 0.f, 0.f);
}
__global__ void scatter_add_kernel(const float4* __restrict__ upd,
                                   const int4* __restrict__ mask,
                                   float* __restrict__ out, int n4) {
    int i = blockIdx.x * blockDim.x + threadIdx.x;
    if (i < n4) {
        float4 u = upd[i];
        int4 m = mask[i];
        atomicAdd(out + m.x, u.x);
        atomicAdd(out + m.y, u.y);
        atomicAdd(out + m.z, u.z);
        atomicAdd(out + m.w, u.w);
    }
}

extern "C" void kernel_launch(void* const* d_in, const int* in_sizes, int n_in,
                              void* d_out, int out_size, void* d_ws, size_t ws_size,
                              hipStream_t stream) {
    const float* updates = (const float*)d_in[0];
    const int*   mask    = (const int*)d_in[1];
    float* out = (float*)d_out;
    const int n  = in_sizes[0];          // 8,388,608
    const int n4 = n >> 2;
    const int o4 = out_size >> 2;

    const size_t need = (size_t)P1B * IPB * sizeof(uint2)   // pairs: 64 MiB
                      + (size_t)P1B * NB * sizeof(unsigned);// table:  8 MiB
    if (ws_size >= need && out_size == NB * RB && n == P1B * IPB) {
        uint2* pairs = (uint2*)d_ws;
        unsigned int* table = (unsigned int*)((char*)d_ws + (size_t)P1B * IPB * sizeof(uint2));

        partition_kernel<<<P1B, 256, 0, stream>>>(
            (const float4*)updates, (const int4*)mask, table, pairs);
        unbin_kernel<<<NB, 256, RB * sizeof(float), stream>>>(
            table, pairs, (float4*)out);
    } else {
        zero_out_kernel<<<(o4 + 255) / 256, 256, 0, stream>>>((float4*)out, o4);
        scatter_add_kernel<<<(n4 + 255) / 256, 256, 0, stream>>>(
            (const float4*)updates, (const int4*)mask, out, n4);
    }
}